// Round 3
// baseline (288.654 us; speedup 1.0000x reference)
//
#include <hip/hip_runtime.h>
#include <hip/hip_fp16.h>
#include <math.h>

#define DEPTH 6
#define HEADS 8
#define BB    2
#define NN    128
#define EE    160
#define NF    127
#define DIMM  128
#define INNER 512
#define NNODE 256

typedef _Float16 h2f16 __attribute__((ext_vector_type(2)));

#if defined(__has_builtin)
#if __has_builtin(__builtin_amdgcn_fdot2)
#define HAVE_FDOT2 1
#endif
#endif

__device__ __forceinline__ float fdot2f(h2f16 a, h2f16 b, float c) {
#ifdef HAVE_FDOT2
    return __builtin_amdgcn_fdot2(a, b, c, false);
#else
    return c + (float)a.x * (float)b.x + (float)a.y * (float)b.y;
#endif
}

__device__ __forceinline__ void gload16(const void* g, void* l) {
    __builtin_amdgcn_global_load_lds((const __attribute__((address_space(1))) void*)g,
                                     (__attribute__((address_space(3))) void*)l,
                                     16, 0, 0);
}

// s_waitcnt: vmcnt<=N, exp/lgkm unconstrained. gfx9 encoding:
// vmcnt[3:0]=bits3:0, exp=bits6:4, lgkm=bits11:8, vmcnt[5:4]=bits15:14.
template <int N>
__device__ __forceinline__ void wait_vm() {
    __builtin_amdgcn_s_waitcnt((0xF << 8) | (7 << 4) | (N & 0xF) | ((N >> 4) << 14));
}
// drain this wave's LDS ops before slice overwrite
__device__ __forceinline__ void wait_lgkm0() { __builtin_amdgcn_s_waitcnt(0xC07F); }
__device__ __forceinline__ void sbar0() { __builtin_amdgcn_sched_barrier(0); }

// 4 KB contiguous chunk: 4 x (1 KB) DMA calls. lds wave-uniform, linear dest.
__device__ __forceinline__ void stage4c(const char* g, char* lds, int ln) {
#pragma unroll
    for (int i = 0; i < 4; i++)
        gload16(g + i * 1024 + ln * 16, lds + i * 1024);
}
// 4 KB chunk of 8 half-rows (512 B each) with global row stride rs bytes.
// Call i stages rows 2i (lanes 0-31) and 2i+1 (lanes 32-63) into 1 KB of LDS;
// per-lane GLOBAL address carries the split, LDS dest stays linear (legal).
__device__ __forceinline__ void stage4h(const char* g, int rs, char* lds, int ln) {
#pragma unroll
    for (int i = 0; i < 4; i++)
        gload16(g + (size_t)(2 * i + (ln >> 5)) * rs + (ln & 31) * 16, lds + i * 1024);
}

// ---- pipelined GEMV units, 16 waves ----
// NK: 0 = no next-phase staging, 1 = contiguous next chunk, 2 = half-row next.
// Discipline: at entry this wave's chunks A,B (4 calls each) are in flight.
// vm<=4 -> A landed. compute A. drain lds. stage A'. vm<=4 -> B landed. compute B.
// stage B'. (in-order vmem retirement makes the counted wait exact)

// C=512, K=128. Wave w: kg=w>>1 owns K-rows [kg*16,kg*16+16), ch=w&1 owns cols
// [ch*256,ch*256+256). Slice = 16 rows x 512 B. Lane: 4 cols, 1 ds_read_b64/row.
template <int NK>
__device__ __forceinline__ void gemv512x(const float* act, float* wbuf,
                                         float* s_part, int w, int ln,
                                         const char* nextA, const char* nextB,
                                         int nextRS) {
    int kg = w >> 1;
    float4 acc = {0, 0, 0, 0};
    const float2* w2 = (const float2*)wbuf;
    wait_vm<4>();
#pragma unroll
    for (int r = 0; r < 8; r++) {
        float2 raw = w2[r * 64 + ln];
        const __half2* hp = (const __half2*)&raw;
        float2 p0 = __half22float2(hp[0]), p1 = __half22float2(hp[1]);
        float a = act[kg * 16 + r];
        acc.x += a * p0.x; acc.y += a * p0.y; acc.z += a * p1.x; acc.w += a * p1.y;
    }
    wait_lgkm0(); sbar0();
    if (NK == 1)      { stage4c(nextA, (char*)wbuf, ln);         wait_vm<4>(); }
    else if (NK == 2) { stage4h(nextA, nextRS, (char*)wbuf, ln); wait_vm<4>(); }
    else              { wait_vm<0>(); }
#pragma unroll
    for (int r = 8; r < 16; r++) {
        float2 raw = w2[r * 64 + ln];
        const __half2* hp = (const __half2*)&raw;
        float2 p0 = __half22float2(hp[0]), p1 = __half22float2(hp[1]);
        float a = act[kg * 16 + r];
        acc.x += a * p0.x; acc.y += a * p0.y; acc.z += a * p1.x; acc.w += a * p1.y;
    }
    wait_lgkm0(); sbar0();
    if (NK == 1)      stage4c(nextB, (char*)wbuf + 4096, ln);
    else if (NK == 2) stage4h(nextB, nextRS, (char*)wbuf + 4096, ln);
    ((float4*)(s_part + w * 256))[ln] = acc;
}

// C=128, K=512. Wave w owns K-rows [w*32,w*32+32); slice contiguous 8 KB
// (row = 256 B). Lane: 2 cols, 1 ds_read_b32/row.
template <int NK>
__device__ __forceinline__ void gemv128x(const float* act, float* wbuf,
                                         float* s_part, int w, int ln,
                                         const char* nextA, const char* nextB,
                                         int nextRS) {
    float2 acc = {0, 0};
    wait_vm<4>();
#pragma unroll 8
    for (int r = 0; r < 16; r++) {
        float raw = wbuf[r * 64 + ln];
        float2 p = __half22float2(*(const __half2*)&raw);
        float a = act[w * 32 + r];
        acc.x += a * p.x; acc.y += a * p.y;
    }
    wait_lgkm0(); sbar0();
    if (NK == 1)      { stage4c(nextA, (char*)wbuf, ln);         wait_vm<4>(); }
    else if (NK == 2) { stage4h(nextA, nextRS, (char*)wbuf, ln); wait_vm<4>(); }
    else              { wait_vm<0>(); }
#pragma unroll 8
    for (int r = 16; r < 32; r++) {
        float raw = wbuf[r * 64 + ln];
        float2 p = __half22float2(*(const __half2*)&raw);
        float a = act[w * 32 + r];
        acc.x += a * p.x; acc.y += a * p.y;
    }
    wait_lgkm0(); sbar0();
    if (NK == 1)      stage4c(nextB, (char*)wbuf + 4096, ln);
    else if (NK == 2) stage4h(nextB, nextRS, (char*)wbuf + 4096, ln);
    s_part[w * 128 + ln * 2]     = acc.x;
    s_part[w * 128 + ln * 2 + 1] = acc.y;
}

// N-value block reduce (16 waves); results broadcast into vals[].
template <int N>
__device__ __forceinline__ void block_reduce_n(float* vals, float* sbuf) {
#pragma unroll
    for (int off = 32; off > 0; off >>= 1)
#pragma unroll
        for (int q = 0; q < N; q++) vals[q] += __shfl_xor(vals[q], off, 64);
    int wave = threadIdx.x >> 6;
    if ((threadIdx.x & 63) == 0)
#pragma unroll
        for (int q = 0; q < N; q++) sbuf[wave * N + q] = vals[q];
    __syncthreads();
#pragma unroll
    for (int q = 0; q < N; q++) {
        float r = 0.0f;
#pragma unroll
        for (int g = 0; g < 16; g++) r += sbuf[g * N + q];
        vals[q] = r;
    }
    __syncthreads();
}

__device__ __forceinline__ float gelu_exact(float a) {
    return 0.5f * a * (1.0f + erff(a * 0.70710678f));
}

// ---------- kernels ----------

__global__ __launch_bounds__(512) void k_cvt(const float* Wq, const float* Wkv,
                                             const float* Wo, const float* W1,
                                             const float* W2,
                                             __half* hWq, __half* hWkv, __half* hWo,
                                             __half* hW1, __half* hW2,
                                             const float* blin, float* out) {
    if (blockIdx.x == 0 && threadIdx.x == 0) out[0] = 256.0f * blin[0];
    int g = blockIdx.x * 512 + threadIdx.x;
    const float4* src; __half* dst; int off;
    if (g < 98304)       { src = (const float4*)Wq;  dst = hWq;  off = g; }
    else if (g < 294912) { src = (const float4*)Wkv; dst = hWkv; off = g - 98304; }
    else if (g < 393216) { src = (const float4*)Wo;  dst = hWo;  off = g - 294912; }
    else if (g < 491520) { src = (const float4*)W1;  dst = hW1;  off = g - 393216; }
    else                 { src = (const float4*)W2;  dst = hW2;  off = g - 491520; }
    float4 v = src[off];
    __half2* d2 = (__half2*)(dst + (size_t)off * 4);
    d2[0] = __floats2half2_rn(v.x, v.y);
    d2[1] = __floats2half2_rn(v.z, v.w);
}

__global__ __launch_bounds__(1024, 4) void k_pre(const int* indices, const float* noise,
                                                 const float* atom_emb,
                                                 const float* ln1_g, const float* ln1_b,
                                                 const __half* hWq, const float* bq,
                                                 const __half* hWkv, const float* bkv,
                                                 float* nodes, float* qb,
                                                 __half* hk, __half* hv) {
    int bn = blockIdx.x;
    int t  = threadIdx.x;
    int d  = t & 127;
    bool own = (t < 128);
    int w = t >> 6, ln = t & 63;
    int kg = w >> 1, ch = w & 1;
    __shared__ float arena[32768];     // 16 waves x 8 KB slices
    __shared__ float s_xn[128];
    __shared__ float s_red[96];
    __shared__ float s_part[4096];
    float* wbuf = arena + w * 2048;

    const char* WqL  = (const char*)hWq;
    const char* WkvL = (const char*)hWkv;

    // stage Wq slice chunks; DMA flies over gather + LN
    stage4h(WqL + (size_t)(kg * 16) * 1024 + ch * 512, 1024, (char*)wbuf, ln);
    stage4h(WqL + (size_t)(kg * 16 + 8) * 1024 + ch * 512, 1024, (char*)wbuf + 4096, ln);

    float nd = 0.0f;
    if (own) {
        int idx = indices[bn];
        nd = (d < NF) ? atom_emb[idx * NF + d] : noise[0];
        nodes[bn * DIMM + d] = nd;
    }
    float vals[2] = {own ? nd : 0.0f, own ? nd * nd : 0.0f};
    block_reduce_n<2>(vals, s_red);
    float m   = vals[0] * (1.0f / 128.0f);
    float var = vals[1] * (1.0f / 128.0f) - m * m;
    if (own) s_xn[d] = (nd - m) * rsqrtf(var + 1e-5f) * ln1_g[d] + ln1_b[d];
    __syncthreads();

    // Wq (stages Wk chunks mid-flight)
    gemv512x<2>(s_xn, wbuf, s_part, w, ln,
                WkvL + (size_t)(kg * 16) * 2048 + ch * 512,
                WkvL + (size_t)(kg * 16 + 8) * 2048 + ch * 512, 2048);
    __syncthreads();
    if (t < 512) {
        int lc = t & 255, cch = t >> 8;
        float q = bq[t];
#pragma unroll
        for (int g = 0; g < 8; g++) q += s_part[(g * 2 + cch) * 256 + lc];
        qb[(size_t)bn * INNER + t] = q;
    }
    __syncthreads();

    // Wk (stages Wv chunks)
    gemv512x<2>(s_xn, wbuf, s_part, w, ln,
                WkvL + (size_t)(kg * 16) * 2048 + 1024 + ch * 512,
                WkvL + (size_t)(kg * 16 + 8) * 2048 + 1024 + ch * 512, 2048);
    __syncthreads();
    if (t < 512) {
        int lc = t & 255, cch = t >> 8;
        float k = bkv[t];
#pragma unroll
        for (int g = 0; g < 8; g++) k += s_part[(g * 2 + cch) * 256 + lc];
        hk[(size_t)bn * INNER + t] = __float2half(k);
    }
    __syncthreads();

    // Wv (tail)
    gemv512x<0>(s_xn, wbuf, s_part, w, ln, nullptr, nullptr, 0);
    __syncthreads();
    if (t < 512) {
        int lc = t & 255, cch = t >> 8;
        float v = bkv[INNER + t];
#pragma unroll
        for (int g = 0; g < 8; g++) v += s_part[(g * 2 + cch) * 256 + lc];
        hv[(size_t)bn * INNER + t] = __float2half(v);
    }
}

__global__ __launch_bounds__(1024, 4) void k_layer(int l,
        const float* coords, const int* bonds,
        const float* We, const float* be,
        float* qb, const __half* hkin, const __half* hvin,
        __half* hkout, __half* hvout,
        const __half* hWo, const float* bo, const float* Wg1,
        const float* ln2_g, const float* ln2_b,
        const __half* hW1, const float* b1,
        const __half* hW2, const float* b2,
        const float* Wg2,
        const float* ln1_g, const float* ln1_b,
        const __half* hWq, const float* bq,
        const __half* hWkv, const float* bkv,
        float* nodes, const float* Wlin, float* out) {
    int bn = blockIdx.x;
    int b = bn >> 7, i = bn & 127;
    int t = threadIdx.x;
    int d = t & 127;
    bool own = (t < 128);
    int w = t >> 6, ln = t & 63;
    int kg = w >> 1, ch = w & 1;

    __shared__ float arena[32768];     // 16 waves x 8 KB weight slices
    __shared__ float scoord[384];
    __shared__ float sedge[384];
    __shared__ int   sadj[128];
    __shared__ float s_l[128];
    __shared__ float s_ao[512];
    __shared__ float s_h[512];
    __shared__ float s_xn[128];
    __shared__ float s_red[96];
    __shared__ float s_part[4096];
    float* wbuf = arena + w * 2048;

    const char* WoL  = (const char*)(hWo + (size_t)l * INNER * DIMM);
    const char* W1L  = (const char*)(hW1 + (size_t)l * DIMM * 4 * DIMM);
    const char* W2L  = (const char*)(hW2 + (size_t)l * 4 * DIMM * DIMM);
    const char* WqL  = (const char*)(hWq + (size_t)(l + 1) * DIMM * INNER);
    const char* WkvL = (const char*)(hWkv + (size_t)(l + 1) * DIMM * 2 * INNER);

    // stage Wo slice (contiguous: wave owns rows w*32.., row=256 B); DMA flies
    // over the whole attention phase
    stage4c(WoL + w * 8192, (char*)wbuf, ln);
    stage4c(WoL + w * 8192 + 4096, (char*)wbuf + 4096, ln);

    // ---------- attention: wave w owns j in [w*8, w*8+8); 64 lanes = 512 dims ----------
    const float4* qR4 = (const float4*)(qb + (size_t)bn * INNER);
    const float4* WeR = (const float4*)(We + (size_t)l * 3 * INNER);
    float4 qa  = qR4[ln * 2],        qz  = qR4[ln * 2 + 1];
    float4 w0a = WeR[ln * 2],        w0z = WeR[ln * 2 + 1];
    float4 w1a = WeR[128 + ln * 2],  w1z = WeR[129 + ln * 2];
    float4 w2a = WeR[256 + ln * 2],  w2z = WeR[257 + ln * 2];
    float4 bea = ((const float4*)(be + (size_t)l * INNER))[ln * 2];
    float4 bez = ((const float4*)(be + (size_t)l * INNER))[ln * 2 + 1];
    float res = own ? nodes[bn * DIMM + d] : 0.0f;
    h2f16 qh0 = {(_Float16)qa.x, (_Float16)qa.y};
    h2f16 qh1 = {(_Float16)qa.z, (_Float16)qa.w};
    h2f16 qh2 = {(_Float16)qz.x, (_Float16)qz.y};
    h2f16 qh3 = {(_Float16)qz.z, (_Float16)qz.w};
    // per-head q.be (non-bonded j have e == be exactly)
    float c = qa.x * bea.x + qa.y * bea.y + qa.z * bea.z + qa.w * bea.w
            + qz.x * bez.x + qz.y * bez.y + qz.z * bez.z + qz.w * bez.w;
    c += __shfl_xor(c, 1, 64); c += __shfl_xor(c, 2, 64); c += __shfl_xor(c, 4, 64);

    if (t < 3 * NN) scoord[t] = coords[b * 3 * NN + t];
    if (t < NN) sadj[t] = 0;
    __syncthreads();
    if (t < EE) {
        int e0 = bonds[2 * t], e1 = bonds[2 * t + 1];
        if (e0 == i) sadj[e1] = 1;
        if (e1 == i) sadj[e0] = 1;
    }
    __syncthreads();
    if (t < NN) {
        int j = t;
        float msk = sadj[j] ? 1.0f : 0.0f;
        sedge[3 * j + 0] = msk * (scoord[3 * i + 0] - scoord[3 * j + 0]);
        sedge[3 * j + 1] = msk * (scoord[3 * i + 1] - scoord[3 * j + 1]);
        sedge[3 * j + 2] = msk * (scoord[3 * i + 2] - scoord[3 * j + 2]);
    }
    __syncthreads();

    const float4* kR = (const float4*)(hkin + (size_t)b * NN * INNER);   // 8 halves/elt
    const float4* vR = (const float4*)(hvin + (size_t)b * NN * INNER);
    float l_run = 0.0f, S_nb = 0.0f;
    float4 o0 = {0, 0, 0, 0}, o1 = {0, 0, 0, 0};
    int j0 = w * 8;
#pragma unroll
    for (int base = 0; base < 8; base += 4) {
        float4 kraw[4], vraw[4];
#pragma unroll
        for (int p = 0; p < 4; p++) {
            int j = j0 + base + p;
            kraw[p] = kR[j * 64 + ln];
            vraw[p] = vR[j * 64 + ln];
        }
#pragma unroll
        for (int p = 0; p < 4; p++) {
            int j = j0 + base + p;
            const h2f16* kh = (const h2f16*)&kraw[p];
            float s = fdot2f(qh0, kh[0],
                      fdot2f(qh1, kh[1],
                      fdot2f(qh2, kh[2],
                      fdot2f(qh3, kh[3], 0.0f))));
            bool bonded = (sadj[j] != 0);      // wave-uniform branch
            float4 e0, e1;
            if (bonded) {
                float ex = sedge[3 * j], ey = sedge[3 * j + 1], ez = sedge[3 * j + 2];
                e0.x = bea.x + ex * w0a.x + ey * w1a.x + ez * w2a.x;
                e0.y = bea.y + ex * w0a.y + ey * w1a.y + ez * w2a.y;
                e0.z = bea.z + ex * w0a.z + ey * w1a.z + ez * w2a.z;
                e0.w = bea.w + ex * w0a.w + ey * w1a.w + ez * w2a.w;
                e1.x = bez.x + ex * w0z.x + ey * w1z.x + ez * w2z.x;
                e1.y = bez.y + ex * w0z.y + ey * w1z.y + ez * w2z.y;
                e1.z = bez.z + ex * w0z.z + ey * w1z.z + ez * w2z.z;
                e1.w = bez.w + ex * w0z.w + ey * w1z.w + ez * w2z.w;
                s += qa.x * e0.x + qa.y * e0.y + qa.z * e0.z + qa.w * e0.w
                   + qz.x * e1.x + qz.y * e1.y + qz.z * e1.z + qz.w * e1.w;
            }
            s += __shfl_xor(s, 1, 64);
            s += __shfl_xor(s, 2, 64);
            s += __shfl_xor(s, 4, 64);
            if (!bonded) s += c;
            float pp = __expf(s * 0.125f);
            l_run += pp;
            const __half2* vh = (const __half2*)&vraw[p];
            float2 v0 = __half22float2(vh[0]), v1 = __half22float2(vh[1]);
            float2 v2 = __half22float2(vh[2]), v3 = __half22float2(vh[3]);
            o0.x += pp * v0.x; o0.y += pp * v0.y; o0.z += pp * v1.x; o0.w += pp * v1.y;
            o1.x += pp * v2.x; o1.y += pp * v2.y; o1.z += pp * v3.x; o1.w += pp * v3.y;
            if (bonded) {
                o0.x += pp * e0.x; o0.y += pp * e0.y; o0.z += pp * e0.z; o0.w += pp * e0.w;
                o1.x += pp * e1.x; o1.y += pp * e1.y; o1.z += pp * e1.z; o1.w += pp * e1.w;
            } else S_nb += pp;
        }
    }
    // fold the shared be contribution of all non-bonded j
    o0.x += S_nb * bea.x; o0.y += S_nb * bea.y; o0.z += S_nb * bea.z; o0.w += S_nb * bea.w;
    o1.x += S_nb * bez.x; o1.y += S_nb * bez.y; o1.z += S_nb * bez.z; o1.w += S_nb * bez.w;
    if ((ln & 7) == 0) s_l[w * 8 + (ln >> 3)] = l_run;

    // two-round o-combine through the 16 KB s_part (16 waves x 512 > s_part)
    if (w < 8) {
        ((float4*)(s_part + w * 512))[ln * 2]     = o0;
        ((float4*)(s_part + w * 512))[ln * 2 + 1] = o1;
    }
    __syncthreads();
    float oacc = 0.0f;
    if (t < 512) {
#pragma unroll
        for (int g = 0; g < 8; g++) oacc += s_part[g * 512 + t];
    }
    __syncthreads();
    if (w >= 8) {
        ((float4*)(s_part + (w - 8) * 512))[ln * 2]     = o0;
        ((float4*)(s_part + (w - 8) * 512))[ln * 2 + 1] = o1;
    }
    __syncthreads();
    if (t < 512) {
#pragma unroll
        for (int g = 0; g < 8; g++) oacc += s_part[g * 512 + t];
        int h = t >> 6;
        float lsum = 0.0f;
#pragma unroll
        for (int g = 0; g < 16; g++) lsum += s_l[g * 8 + h];
        s_ao[t] = oacc / lsum;
    }
    __syncthreads();

    // ---------- Wo [512 x 128], K-split (stages W1 chunks mid-flight) ----------
    gemv128x<2>(s_ao, wbuf, s_part, w, ln,
                W1L + (size_t)(kg * 16) * 1024 + ch * 512,
                W1L + (size_t)(kg * 16 + 8) * 1024 + ch * 512, 1024);
    __syncthreads();
    float x = 0.0f;
    if (own) {
        x = bo[l * DIMM + d];
#pragma unroll
        for (int g = 0; g < 16; g++) x += s_part[g * 128 + d];
    }

    // ---------- fused gate1 + LN2 (single reduce pass) ----------
    const float* Wg1_l = Wg1 + l * 3 * DIMM;
    float n1;
    {
        float tex = own ? (x * Wg1_l[d] + res * Wg1_l[DIMM + d]
                           + (x - res) * Wg1_l[2 * DIMM + d]) : 0.0f;
        float vals[6] = {tex,
                         own ? x : 0.0f, own ? x * x : 0.0f,
                         own ? x * res : 0.0f,
                         own ? res : 0.0f, own ? res * res : 0.0f};
        block_reduce_n<6>(vals, s_red);
        float g1 = 1.0f / (1.0f + __expf(-vals[0]));
        float sn  = g1 * vals[1] + (1.0f - g1) * vals[4];
        float sn2 = g1 * g1 * vals[2] + 2.0f * g1 * (1.0f - g1) * vals[3]
                  + (1.0f - g1) * (1.0f - g1) * vals[5];
        float m   = sn * (1.0f / 128.0f);
        float var = sn2 * (1.0f / 128.0f) - m * m;
        n1 = x * g1 + res * (1.0f - g1);
        if (own) s_xn[d] = (n1 - m) * rsqrtf(var + 1e-5f) * ln2_g[l * DIMM + d]
                         + ln2_b[l * DIMM + d];
    }
    __syncthreads();

    // ---------- W1 [128 x 512] + gelu (stages W2 chunks mid-flight) ----------
    gemv512x<1>(s_xn, wbuf, s_part, w, ln,
                W2L + w * 8192, W2L + w * 8192 + 4096, 0);
    __syncthreads();
    if (t < 512) {
        int lc = t & 255, cch = t >> 8;
        float a = b1[l * 4 * DIMM + t];
#pragma unroll
        for (int g = 0; g < 8; g++) a += s_part[(g * 2 + cch) * 256 + lc];
        s_h[t] = gelu_exact(a);
    }
    __syncthreads();

    // ---------- W2 [512 x 128], K-split (stages next-layer Wq if needed) ----------
    if (l < DEPTH - 1)
        gemv128x<2>(s_h, wbuf, s_part, w, ln,
                    WqL + (size_t)(kg * 16) * 1024 + ch * 512,
                    WqL + (size_t)(kg * 16 + 8) * 1024 + ch * 512, 1024);
    else
        gemv128x<0>(s_h, wbuf, s_part, w, ln, nullptr, nullptr, 0);
    __syncthreads();
    float y = 0.0f;
    if (own) {
        y = b2[l * DIMM + d];
#pragma unroll
        for (int g = 0; g < 16; g++) y += s_part[g * 128 + d];
    }

    const float* Wg2_l = Wg2 + l * 3 * DIMM;
    if (l < DEPTH - 1) {
        // ---------- fused gate2 + LN1' (single reduce pass) ----------
        float tex = own ? (y * Wg2_l[d] + n1 * Wg2_l[DIMM + d]
                           + (y - n1) * Wg2_l[2 * DIMM + d]) : 0.0f;
        float vals[6] = {tex,
                         own ? y : 0.0f, own ? y * y : 0.0f,
                         own ? y * n1 : 0.0f,
                         own ? n1 : 0.0f, own ? n1 * n1 : 0.0f};
        block_reduce_n<6>(vals, s_red);
        float g2 = 1.0f / (1.0f + __expf(-vals[0]));
        float sn  = g2 * vals[1] + (1.0f - g2) * vals[4];
        float sn2 = g2 * g2 * vals[2] + 2.0f * g2 * (1.0f - g2) * vals[3]
                  + (1.0f - g2) * (1.0f - g2) * vals[5];
        float m   = sn * (1.0f / 128.0f);
        float var = sn2 * (1.0f / 128.0f) - m * m;
        float n2 = y * g2 + n1 * (1.0f - g2);
        if (own) {
            nodes[bn * DIMM + d] = n2;
            s_xn[d] = (n2 - m) * rsqrtf(var + 1e-5f) * ln1_g[(l + 1) * DIMM + d]
                    + ln1_b[(l + 1) * DIMM + d];
        }
        __syncthreads();

        // Wq (stages Wk chunks)
        gemv512x<2>(s_xn, wbuf, s_part, w, ln,
                    WkvL + (size_t)(kg * 16) * 2048 + ch * 512,
                    WkvL + (size_t)(kg * 16 + 8) * 2048 + ch * 512, 2048);
        __syncthreads();
        if (t < 512) {
            int lc = t & 255, cch = t >> 8;
            float q = bq[(l + 1) * INNER + t];
#pragma unroll
            for (int g = 0; g < 8; g++) q += s_part[(g * 2 + cch) * 256 + lc];
            qb[(size_t)bn * INNER + t] = q;
        }
        __syncthreads();

        // Wk (stages Wv chunks)
        gemv512x<2>(s_xn, wbuf, s_part, w, ln,
                    WkvL + (size_t)(kg * 16) * 2048 + 1024 + ch * 512,
                    WkvL + (size_t)(kg * 16 + 8) * 2048 + 1024 + ch * 512, 2048);
        __syncthreads();
        if (t < 512) {
            int lc = t & 255, cch = t >> 8;
            float k = bkv[(l + 1) * 2 * INNER + t];
#pragma unroll
            for (int g = 0; g < 8; g++) k += s_part[(g * 2 + cch) * 256 + lc];
            hkout[(size_t)bn * INNER + t] = __float2half(k);
        }
        __syncthreads();

        // Wv (tail)
        gemv512x<0>(s_xn, wbuf, s_part, w, ln, nullptr, nullptr, 0);
        __syncthreads();
        if (t < 512) {
            int lc = t & 255, cch = t >> 8;
            float v = bkv[(l + 1) * 2 * INNER + INNER + t];
#pragma unroll
            for (int g = 0; g < 8; g++) v += s_part[(g * 2 + cch) * 256 + lc];
            hvout[(size_t)bn * INNER + t] = __float2half(v);
        }
    } else {
        // ---------- fused gate2 + final contribution ----------
        float wl = own ? Wlin[d] : 0.0f;
        float tex = own ? (y * Wg2_l[d] + n1 * Wg2_l[DIMM + d]
                           + (y - n1) * Wg2_l[2 * DIMM + d]) : 0.0f;
        float vals[3] = {tex, y * wl, n1 * wl};
        block_reduce_n<3>(vals, s_red);
        float g2 = 1.0f / (1.0f + __expf(-vals[0]));
        float tot = g2 * vals[1] + (1.0f - g2) * vals[2];
        if (t == 0) atomicAdd(out, tot);
    }
}

extern "C" void kernel_launch(void* const* d_in, const int* in_sizes, int n_in,
                              void* d_out, int out_size, void* d_ws, size_t ws_size,
                              hipStream_t stream) {
    const int*   indices = (const int*)d_in[0];
    const float* coords  = (const float*)d_in[1];
    const int*   bonds   = (const int*)d_in[2];
    const float* noise   = (const float*)d_in[3];
    const float* atom_emb= (const float*)d_in[4];
    const float* ln1_g   = (const float*)d_in[5];
    const float* ln1_b   = (const float*)d_in[6];
    const float* Wq      = (const float*)d_in[7];
    const float* bq      = (const float*)d_in[8];
    const float* Wkv     = (const float*)d_in[9];
    const float* bkv     = (const float*)d_in[10];
    const float* We      = (const float*)d_in[11];
    const float* be      = (const float*)d_in[12];
    const float* Wo      = (const float*)d_in[13];
    const float* bo      = (const float*)d_in[14];
    const float* Wg1     = (const float*)d_in[15];
    const float* ln2_g   = (const float*)d_in[16];
    const float* ln2_b   = (const float*)d_in[17];
    const float* W1      = (const float*)d_in[18];
    const float* b1      = (const float*)d_in[19];
    const float* W2      = (const float*)d_in[20];
    const float* b2      = (const float*)d_in[21];
    const float* Wg2     = (const float*)d_in[22];
    const float* Wlin    = (const float*)d_in[23];
    const float* blin    = (const float*)d_in[24];

    float*  ws    = (float*)d_ws;
    float*  nodes = ws;                         // 32768 f
    float*  qb    = nodes + NNODE * DIMM;       // 131072 f
    __half* hkb   = (__half*)(qb + NNODE * INNER);  // 2 slabs x 131072 halves
    __half* hvb   = hkb + 2 * NNODE * INNER;
    __half* hWq   = hvb + 2 * NNODE * INNER;
    __half* hWkv  = hWq + DEPTH * DIMM * INNER;
    __half* hWo   = hWkv + DEPTH * DIMM * 2 * INNER;
    __half* hW1   = hWo + DEPTH * INNER * DIMM;
    __half* hW2   = hW1 + DEPTH * DIMM * 4 * DIMM;

    k_cvt<<<1152, 512, 0, stream>>>(Wq, Wkv, Wo, W1, W2, hWq, hWkv, hWo, hW1, hW2,
                                    blin, (float*)d_out);
    k_pre<<<NNODE, 1024, 0, stream>>>(indices, noise, atom_emb, ln1_g, ln1_b,
                                      hWq, bq, hWkv, bkv, nodes, qb, hkb, hvb);
    for (int l = 0; l < DEPTH; l++) {
        const __half* hkin = hkb + (size_t)(l & 1) * NNODE * INNER;
        const __half* hvin = hvb + (size_t)(l & 1) * NNODE * INNER;
        __half* hkout = hkb + (size_t)((l + 1) & 1) * NNODE * INNER;
        __half* hvout = hvb + (size_t)((l + 1) & 1) * NNODE * INNER;
        k_layer<<<NNODE, 1024, 0, stream>>>(l, coords, bonds, We, be,
                                            qb, hkin, hvin, hkout, hvout,
                                            hWo, bo, Wg1, ln2_g, ln2_b, hW1, b1, hW2, b2,
                                            Wg2, ln1_g, ln1_b, hWq, bq, hWkv, bkv,
                                            nodes, Wlin, (float*)d_out);
    }
}

// Round 4
// 245.321 us; speedup vs baseline: 1.1766x; 1.1766x over previous
//
#include <hip/hip_runtime.h>
#include <hip/hip_fp16.h>
#include <math.h>

#define DEPTH 6
#define NN    128
#define EE    160
#define NF    127
#define DIMM  128
#define INNER 512
#define NNODE 256

typedef _Float16 h2f16 __attribute__((ext_vector_type(2)));

#if defined(__has_builtin)
#if __has_builtin(__builtin_amdgcn_fdot2)
#define HAVE_FDOT2 1
#endif
#endif

__device__ __forceinline__ float fdot2f(h2f16 a, h2f16 b, float c) {
#ifdef HAVE_FDOT2
    return __builtin_amdgcn_fdot2(a, b, c, false);
#else
    return c + (float)a.x * (float)b.x + (float)a.y * (float)b.y;
#endif
}

__device__ __forceinline__ void gload16(const void* g, void* l) {
    __builtin_amdgcn_global_load_lds((const __attribute__((address_space(1))) void*)g,
                                     (__attribute__((address_space(3))) void*)l,
                                     16, 0, 0);
}

// s_waitcnt: vmcnt<=N, exp/lgkm unconstrained. gfx9 encoding:
// vmcnt[3:0]=bits3:0, exp=bits6:4, lgkm=bits11:8, vmcnt[5:4]=bits15:14.
template <int N>
__device__ __forceinline__ void wait_vm() {
    __builtin_amdgcn_s_waitcnt((0xF << 8) | (7 << 4) | (N & 0xF) | ((N >> 4) << 14));
}
__device__ __forceinline__ void wait_lgkm0() { __builtin_amdgcn_s_waitcnt(0xC07F); }
__device__ __forceinline__ void sbar0() { __builtin_amdgcn_sched_barrier(0); }

// Stage a contiguous 16 KB wave slice: 16 x (1 KB) DMA calls, linear LDS dest.
__device__ __forceinline__ void stage16(const char* g, char* lds, int ln) {
#pragma unroll
    for (int i = 0; i < 16; i++)
        gload16(g + i * 1024 + ln * 16, lds + i * 1024);
}

// ---- transposed-weight GEMV units (no cross-wave K-combine) ----
// Weight slab layout (written by k_cvt, staged linearly by DMA):
//   per wave slice = 16 KB; lane ln owns 256 B at ln*256; 16-B block of
//   rows [8i, 8i+8) of lane's column stored at slot ((i + ln) & 15).
// Per-16-lane group the slots cover all 16 positions -> 2 lanes/bank (free).

// C=512, K=128. Lane output col = w*64 + ln. x = 128 halves (broadcast reads).
template <int NSTAGE>
__device__ __forceinline__ float gemv512T(const __half* s_xh, const float* wbuf,
                                          const char* nextG, char* wbufc, int ln) {
    const float4* W = (const float4*)((const char*)wbuf + ln * 256);
    const float4* X = (const float4*)s_xh;
    float acc = 0.0f;
    float4 wr[8], xr[8];
#pragma unroll
    for (int i = 0; i < 8; i++) { wr[i] = W[(i + ln) & 15]; xr[i] = X[i]; }
#pragma unroll
    for (int i = 0; i < 8; i++) {
        const h2f16* wh = (const h2f16*)&wr[i];
        const h2f16* xh = (const h2f16*)&xr[i];
        acc = fdot2f(xh[0], wh[0], acc); acc = fdot2f(xh[1], wh[1], acc);
        acc = fdot2f(xh[2], wh[2], acc); acc = fdot2f(xh[3], wh[3], acc);
    }
    float4 wr2[8], xr2[8];
#pragma unroll
    for (int i = 0; i < 8; i++) { wr2[i] = W[(i + 8 + ln) & 15]; xr2[i] = X[i + 8]; }
    if (NSTAGE) {
        sbar0();          // pin reads above
        wait_lgkm0();     // all our ds_reads retired -> safe to overwrite slice
        sbar0();          // pin DMA below the wait
        stage16(nextG, wbufc, ln);
    }
#pragma unroll
    for (int i = 0; i < 8; i++) {
        const h2f16* wh = (const h2f16*)&wr2[i];
        const h2f16* xh = (const h2f16*)&xr2[i];
        acc = fdot2f(xh[0], wh[0], acc); acc = fdot2f(xh[1], wh[1], acc);
        acc = fdot2f(xh[2], wh[2], acc); acc = fdot2f(xh[3], wh[3], acc);
    }
    return acc;
}

// C=128, K=512. Lane: col = w*16 + (ln>>2), K-quarter kq = ln&3 (rows kq*128..).
// x = 512 halves stored kq-padded: half index = (row>>7)*136 + (row&127).
// Caller combines the 4 partials with shfl_xor(1) + shfl_xor(2).
template <int NSTAGE>
__device__ __forceinline__ float gemv128T(const __half* s_xp, const float* wbuf,
                                          const char* nextG, char* wbufc, int ln) {
    int kq = ln & 3;
    const float4* W = (const float4*)((const char*)wbuf + ln * 256);
    const float4* X = (const float4*)((const char*)s_xp + kq * 272);
    float acc = 0.0f;
    float4 wr[8], xr[8];
#pragma unroll
    for (int i = 0; i < 8; i++) { wr[i] = W[(i + ln) & 15]; xr[i] = X[i]; }
#pragma unroll
    for (int i = 0; i < 8; i++) {
        const h2f16* wh = (const h2f16*)&wr[i];
        const h2f16* xh = (const h2f16*)&xr[i];
        acc = fdot2f(xh[0], wh[0], acc); acc = fdot2f(xh[1], wh[1], acc);
        acc = fdot2f(xh[2], wh[2], acc); acc = fdot2f(xh[3], wh[3], acc);
    }
    float4 wr2[8], xr2[8];
#pragma unroll
    for (int i = 0; i < 8; i++) { wr2[i] = W[(i + 8 + ln) & 15]; xr2[i] = X[i + 8]; }
    if (NSTAGE) {
        sbar0();
        wait_lgkm0();
        sbar0();
        stage16(nextG, wbufc, ln);
    }
#pragma unroll
    for (int i = 0; i < 8; i++) {
        const h2f16* wh = (const h2f16*)&wr2[i];
        const h2f16* xh = (const h2f16*)&xr2[i];
        acc = fdot2f(xh[0], wh[0], acc); acc = fdot2f(xh[1], wh[1], acc);
        acc = fdot2f(xh[2], wh[2], acc); acc = fdot2f(xh[3], wh[3], acc);
    }
    return acc;
}

// N-value block reduce (8 waves); results broadcast into vals[].
template <int N>
__device__ __forceinline__ void block_reduce_n(float* vals, float* sbuf) {
#pragma unroll
    for (int off = 32; off > 0; off >>= 1)
#pragma unroll
        for (int q = 0; q < N; q++) vals[q] += __shfl_xor(vals[q], off, 64);
    int wave = threadIdx.x >> 6;
    if ((threadIdx.x & 63) == 0)
#pragma unroll
        for (int q = 0; q < N; q++) sbuf[wave * N + q] = vals[q];
    __syncthreads();
#pragma unroll
    for (int q = 0; q < N; q++) {
        float r = 0.0f;
#pragma unroll
        for (int g = 0; g < 8; g++) r += sbuf[g * N + q];
        vals[q] = r;
    }
    __syncthreads();
}

__device__ __forceinline__ float gelu_exact(float a) {
    return 0.5f * a * (1.0f + erff(a * 0.70710678f));
}

// ---------- k_cvt: f32 row-major -> f16 transposed+swizzled wave slices ----------
// 288 blocks = 6 layers x 6 matrices x 8 wave-slices.
// C=512-type (Wq,Wk,Wv,W1): slice w covers cols [w*64..), ln = col&63.
// C=128-type (Wo,W2):       slice w covers cols [w*16..), ln = (col&15)*4 + kq.
// dest halves: slice + ln*128 + ((i + ln) & 15)*8 + e, block i = 8 rows.
__global__ __launch_bounds__(512) void k_cvt(const float* Wq, const float* Wkv,
                                             const float* Wo, const float* W1,
                                             const float* W2,
                                             __half* hWq, __half* hWkv, __half* hWo,
                                             __half* hW1, __half* hW2,
                                             const float* blin, float* out) {
    if (blockIdx.x == 0 && threadIdx.x == 0) out[0] = 256.0f * blin[0];
    int bid = blockIdx.x;
    int l = bid / 48, rem = bid % 48, mat = rem >> 3, w = rem & 7;
    int t = threadIdx.x;
    const float* src;
    __half* dst;
    int ncols, col0, big;
    if (mat == 0)      { src = Wq  + (size_t)l * 65536;  dst = hWq  + (size_t)l * 65536;          ncols = 512;  col0 = w * 64;       big = 0; }
    else if (mat == 1) { src = Wkv + (size_t)l * 131072; dst = hWkv + (size_t)l * 131072;         ncols = 1024; col0 = w * 64;       big = 0; }
    else if (mat == 2) { src = Wkv + (size_t)l * 131072; dst = hWkv + (size_t)l * 131072 + 65536; ncols = 1024; col0 = 512 + w * 64; big = 0; }
    else if (mat == 3) { src = W1  + (size_t)l * 65536;  dst = hW1  + (size_t)l * 65536;          ncols = 512;  col0 = w * 64;       big = 0; }
    else if (mat == 4) { src = Wo  + (size_t)l * 65536;  dst = hWo  + (size_t)l * 65536;          ncols = 128;  col0 = w * 16;       big = 1; }
    else               { src = W2  + (size_t)l * 65536;  dst = hW2  + (size_t)l * 65536;          ncols = 128;  col0 = w * 16;       big = 1; }
    dst += w * 8192;
#pragma unroll
    for (int p = 0; p < 2; p++) {
        int bi = p * 512 + t;
        int i = bi & 15;
        int ln, c, row0;
        if (!big) { c = bi >> 4; ln = c; row0 = i * 8; }
        else {
            c = bi >> 6;
            int kq = (bi >> 4) & 3;
            ln = c * 4 + kq;
            row0 = kq * 128 + i * 8;
        }
        __align__(16) __half tmp[8];
#pragma unroll
        for (int e = 0; e < 8; e++)
            tmp[e] = __float2half(src[(size_t)(row0 + e) * ncols + col0 + c]);
        *(float4*)&dst[ln * 128 + ((i + ln) & 15) * 8] = *(const float4*)tmp;
    }
}

__global__ __launch_bounds__(512, 1) void k_pre(const int* indices, const float* noise,
                                                const float* atom_emb,
                                                const float* ln1_g, const float* ln1_b,
                                                const __half* hWq, const float* bq,
                                                const __half* hWkv, const float* bkv,
                                                float* nodes, float* qb,
                                                __half* hk, __half* hv) {
    int bn = blockIdx.x;
    int t  = threadIdx.x;
    int d  = t & 127;
    bool own = (t < 128);
    int w = t >> 6, ln = t & 63;
    __shared__ float arena[32768];                 // 8 waves x 16 KB slices
    __shared__ __align__(16) __half s_xh[128];
    __shared__ float s_red[48];
    float* wbuf = arena + w * 4096;

    // stage Wq slice; DMA flies over gather + LN
    stage16((const char*)hWq + w * 16384, (char*)wbuf, ln);

    float nd = 0.0f;
    if (own) {
        int idx = indices[bn];
        nd = (d < NF) ? atom_emb[idx * NF + d] : noise[0];
        nodes[bn * DIMM + d] = nd;
    }
    float vals[2] = {own ? nd : 0.0f, own ? nd * nd : 0.0f};
    block_reduce_n<2>(vals, s_red);
    float m   = vals[0] * (1.0f / 128.0f);
    float var = vals[1] * (1.0f / 128.0f) - m * m;
    if (own) s_xh[d] = __float2half((nd - m) * rsqrtf(var + 1e-5f) * ln1_g[d] + ln1_b[d]);
    __syncthreads();

    int col = w * 64 + ln;
    // Wq (stages Wk mid-phase)
    wait_vm<0>();
    {
        float q = gemv512T<1>(s_xh, wbuf, (const char*)hWkv + w * 16384, (char*)wbuf, ln);
        qb[(size_t)bn * INNER + col] = q + bq[col];
    }
    // Wk (stages Wv)
    wait_vm<0>();
    {
        float k = gemv512T<1>(s_xh, wbuf, (const char*)hWkv + 131072 + w * 16384,
                              (char*)wbuf, ln);
        hk[(size_t)bn * INNER + col] = __float2half(k + bkv[col]);
    }
    // Wv (tail)
    wait_vm<0>();
    {
        float v = gemv512T<0>(s_xh, wbuf, nullptr, nullptr, ln);
        hv[(size_t)bn * INNER + col] = __float2half(v + bkv[INNER + col]);
    }
}

__global__ __launch_bounds__(512, 1) void k_layer(int l,
        const float* coords, const int* bonds,
        const float* We, const float* be,
        float* qb, const __half* hkin, const __half* hvin,
        __half* hkout, __half* hvout,
        const __half* hWo, const float* bo, const float* Wg1,
        const float* ln2_g, const float* ln2_b,
        const __half* hW1, const float* b1,
        const __half* hW2, const float* b2,
        const float* Wg2,
        const float* ln1_g, const float* ln1_b,
        const __half* hWq, const float* bq,
        const __half* hWkv, const float* bkv,
        float* nodes, const float* Wlin, float* out) {
    int bn = blockIdx.x;
    int b = bn >> 7, i = bn & 127;
    int t = threadIdx.x;
    int d = t & 127;
    bool own = (t < 128);
    int w = t >> 6, ln = t & 63;

    __shared__ float arena[32768];     // 8 waves x 16 KB weight slices
    __shared__ float scoord[384];
    __shared__ float sedge[384];
    __shared__ int   sadj[128];
    __shared__ float s_l[64];
    __shared__ __align__(16) __half s_aoh[544];   // kq-padded (4 x 136)
    __shared__ __align__(16) __half s_hh[544];    // kq-padded
    __shared__ __align__(16) __half s_xh[128];
    __shared__ float s_x[128];
    __shared__ float s_red[48];
    __shared__ float s_part[4096];     // attention o-combine only
    float* s_o = s_part;
    float* wbuf = arena + w * 4096;

    const char* WoL  = (const char*)hWo + (size_t)l * 131072 + w * 16384;
    const char* W1L  = (const char*)hW1 + (size_t)l * 131072 + w * 16384;
    const char* W2L  = (const char*)hW2 + (size_t)l * 131072 + w * 16384;
    const char* WqnL = (const char*)hWq + (size_t)(l + 1) * 131072 + w * 16384;
    const char* WknL = (const char*)hWkv + (size_t)(l + 1) * 262144 + w * 16384;
    const char* WvnL = (const char*)hWkv + (size_t)(l + 1) * 262144 + 131072 + w * 16384;

    // stage Wo slice; DMA flies over the whole attention phase
    stage16(WoL, (char*)wbuf, ln);

    // ---------- attention: wave w owns j in [w*16, w*16+16); 64 lanes = 512 dims ----------
    const float4* qR4 = (const float4*)(qb + (size_t)bn * INNER);
    const float4* WeR = (const float4*)(We + (size_t)l * 3 * INNER);
    float4 qa  = qR4[ln * 2],        qz  = qR4[ln * 2 + 1];
    float4 w0a = WeR[ln * 2],        w0z = WeR[ln * 2 + 1];
    float4 w1a = WeR[128 + ln * 2],  w1z = WeR[129 + ln * 2];
    float4 w2a = WeR[256 + ln * 2],  w2z = WeR[257 + ln * 2];
    float4 bea = ((const float4*)(be + (size_t)l * INNER))[ln * 2];
    float4 bez = ((const float4*)(be + (size_t)l * INNER))[ln * 2 + 1];
    float res = own ? nodes[bn * DIMM + d] : 0.0f;
    h2f16 qh0 = {(_Float16)qa.x, (_Float16)qa.y};
    h2f16 qh1 = {(_Float16)qa.z, (_Float16)qa.w};
    h2f16 qh2 = {(_Float16)qz.x, (_Float16)qz.y};
    h2f16 qh3 = {(_Float16)qz.z, (_Float16)qz.w};
    // per-head q.be (non-bonded j have e == be exactly)
    float c = qa.x * bea.x + qa.y * bea.y + qa.z * bea.z + qa.w * bea.w
            + qz.x * bez.x + qz.y * bez.y + qz.z * bez.z + qz.w * bez.w;
    c += __shfl_xor(c, 1, 64); c += __shfl_xor(c, 2, 64); c += __shfl_xor(c, 4, 64);

    if (t < 3 * NN) scoord[t] = coords[b * 3 * NN + t];
    if (t < NN) sadj[t] = 0;
    __syncthreads();
    if (t < EE) {
        int e0 = bonds[2 * t], e1 = bonds[2 * t + 1];
        if (e0 == i) sadj[e1] = 1;
        if (e1 == i) sadj[e0] = 1;
    }
    __syncthreads();
    if (t < NN) {
        int j = t;
        float msk = sadj[j] ? 1.0f : 0.0f;
        sedge[3 * j + 0] = msk * (scoord[3 * i + 0] - scoord[3 * j + 0]);
        sedge[3 * j + 1] = msk * (scoord[3 * i + 1] - scoord[3 * j + 1]);
        sedge[3 * j + 2] = msk * (scoord[3 * i + 2] - scoord[3 * j + 2]);
    }
    __syncthreads();

    const float4* kR = (const float4*)(hkin + (size_t)b * NN * INNER);   // 8 halves/elt
    const float4* vR = (const float4*)(hvin + (size_t)b * NN * INNER);
    float l_run = 0.0f, S_nb = 0.0f;
    float4 o0 = {0, 0, 0, 0}, o1 = {0, 0, 0, 0};
    int j0 = w * 16;
#pragma unroll
    for (int base = 0; base < 16; base += 4) {
        float4 kraw[4], vraw[4];
#pragma unroll
        for (int p = 0; p < 4; p++) {
            int j = j0 + base + p;
            kraw[p] = kR[j * 64 + ln];
            vraw[p] = vR[j * 64 + ln];
        }
#pragma unroll
        for (int p = 0; p < 4; p++) {
            int j = j0 + base + p;
            const h2f16* kh = (const h2f16*)&kraw[p];
            float s = fdot2f(qh0, kh[0],
                      fdot2f(qh1, kh[1],
                      fdot2f(qh2, kh[2],
                      fdot2f(qh3, kh[3], 0.0f))));
            bool bonded = (sadj[j] != 0);      // wave-uniform branch
            float4 e0, e1;
            if (bonded) {
                float ex = sedge[3 * j], ey = sedge[3 * j + 1], ez = sedge[3 * j + 2];
                e0.x = bea.x + ex * w0a.x + ey * w1a.x + ez * w2a.x;
                e0.y = bea.y + ex * w0a.y + ey * w1a.y + ez * w2a.y;
                e0.z = bea.z + ex * w0a.z + ey * w1a.z + ez * w2a.z;
                e0.w = bea.w + ex * w0a.w + ey * w1a.w + ez * w2a.w;
                e1.x = bez.x + ex * w0z.x + ey * w1z.x + ez * w2z.x;
                e1.y = bez.y + ex * w0z.y + ey * w1z.y + ez * w2z.y;
                e1.z = bez.z + ex * w0z.z + ey * w1z.z + ez * w2z.z;
                e1.w = bez.w + ex * w0z.w + ey * w1z.w + ez * w2z.w;
                s += qa.x * e0.x + qa.y * e0.y + qa.z * e0.z + qa.w * e0.w
                   + qz.x * e1.x + qz.y * e1.y + qz.z * e1.z + qz.w * e1.w;
            }
            s += __shfl_xor(s, 1, 64);
            s += __shfl_xor(s, 2, 64);
            s += __shfl_xor(s, 4, 64);
            if (!bonded) s += c;
            float pp = __expf(s * 0.125f);
            l_run += pp;
            const __half2* vh = (const __half2*)&vraw[p];
            float2 v0 = __half22float2(vh[0]), v1 = __half22float2(vh[1]);
            float2 v2 = __half22float2(vh[2]), v3 = __half22float2(vh[3]);
            o0.x += pp * v0.x; o0.y += pp * v0.y; o0.z += pp * v1.x; o0.w += pp * v1.y;
            o1.x += pp * v2.x; o1.y += pp * v2.y; o1.z += pp * v3.x; o1.w += pp * v3.y;
            if (bonded) {
                o0.x += pp * e0.x; o0.y += pp * e0.y; o0.z += pp * e0.z; o0.w += pp * e0.w;
                o1.x += pp * e1.x; o1.y += pp * e1.y; o1.z += pp * e1.z; o1.w += pp * e1.w;
            } else S_nb += pp;
        }
    }
    // fold the shared be contribution of all non-bonded j
    o0.x += S_nb * bea.x; o0.y += S_nb * bea.y; o0.z += S_nb * bea.z; o0.w += S_nb * bea.w;
    o1.x += S_nb * bez.x; o1.y += S_nb * bez.y; o1.z += S_nb * bez.z; o1.w += S_nb * bez.w;
    ((float4*)(s_o + w * 512))[ln * 2]     = o0;
    ((float4*)(s_o + w * 512))[ln * 2 + 1] = o1;
    if ((ln & 7) == 0) s_l[w * 8 + (ln >> 3)] = l_run;
    __syncthreads();
    {
        float o = 0.0f;
#pragma unroll
        for (int g = 0; g < 8; g++) o += s_o[g * 512 + t];
        int h = t >> 6;
        float lsum = 0.0f;
#pragma unroll
        for (int g = 0; g < 8; g++) lsum += s_l[g * 8 + h];
        s_aoh[(t >> 7) * 136 + (t & 127)] = __float2half(o / lsum);
    }
    __syncthreads();

    // ---------- Wo [512 x 128] (stages W1 mid-phase) ----------
    wait_vm<0>();
    {
        float xo = gemv128T<1>(s_aoh, wbuf, W1L, (char*)wbuf, ln);
        xo += __shfl_xor(xo, 1, 64);
        xo += __shfl_xor(xo, 2, 64);
        if ((ln & 3) == 0) s_x[w * 16 + (ln >> 2)] = xo;
    }
    __syncthreads();
    float x = own ? s_x[d] + bo[l * DIMM + d] : 0.0f;

    // ---------- fused gate1 + LN2 (single reduce pass) ----------
    const float* Wg1_l = Wg1 + l * 3 * DIMM;
    float n1;
    {
        float tex = own ? (x * Wg1_l[d] + res * Wg1_l[DIMM + d]
                           + (x - res) * Wg1_l[2 * DIMM + d]) : 0.0f;
        float vals[6] = {tex,
                         own ? x : 0.0f, own ? x * x : 0.0f,
                         own ? x * res : 0.0f,
                         own ? res : 0.0f, own ? res * res : 0.0f};
        block_reduce_n<6>(vals, s_red);
        float g1 = 1.0f / (1.0f + __expf(-vals[0]));
        float sn  = g1 * vals[1] + (1.0f - g1) * vals[4];
        float sn2 = g1 * g1 * vals[2] + 2.0f * g1 * (1.0f - g1) * vals[3]
                  + (1.0f - g1) * (1.0f - g1) * vals[5];
        float m   = sn * (1.0f / 128.0f);
        float var = sn2 * (1.0f / 128.0f) - m * m;
        n1 = x * g1 + res * (1.0f - g1);
        if (own) s_xh[d] = __float2half((n1 - m) * rsqrtf(var + 1e-5f) * ln2_g[l * DIMM + d]
                                        + ln2_b[l * DIMM + d]);
    }
    __syncthreads();

    // ---------- W1 [128 x 512] + gelu (stages W2 mid-phase) ----------
    wait_vm<0>();
    {
        float a1 = gemv512T<1>(s_xh, wbuf, W2L, (char*)wbuf, ln);
        int col = w * 64 + ln;
        float ag = gelu_exact(a1 + b1[l * 4 * DIMM + col]);
        s_hh[(col >> 7) * 136 + (col & 127)] = __float2half(ag);
    }
    __syncthreads();

    // ---------- W2 [512 x 128] (stages next-layer Wq if needed) ----------
    wait_vm<0>();
    {
        float yw;
        if (l < DEPTH - 1) yw = gemv128T<1>(s_hh, wbuf, WqnL, (char*)wbuf, ln);
        else               yw = gemv128T<0>(s_hh, wbuf, nullptr, nullptr, ln);
        yw += __shfl_xor(yw, 1, 64);
        yw += __shfl_xor(yw, 2, 64);
        if ((ln & 3) == 0) s_x[w * 16 + (ln >> 2)] = yw;
    }
    __syncthreads();
    float y = own ? s_x[d] + b2[l * DIMM + d] : 0.0f;

    const float* Wg2_l = Wg2 + l * 3 * DIMM;
    if (l < DEPTH - 1) {
        // ---------- fused gate2 + LN1' (single reduce pass) ----------
        float tex = own ? (y * Wg2_l[d] + n1 * Wg2_l[DIMM + d]
                           + (y - n1) * Wg2_l[2 * DIMM + d]) : 0.0f;
        float vals[6] = {tex,
                         own ? y : 0.0f, own ? y * y : 0.0f,
                         own ? y * n1 : 0.0f,
                         own ? n1 : 0.0f, own ? n1 * n1 : 0.0f};
        block_reduce_n<6>(vals, s_red);
        float g2 = 1.0f / (1.0f + __expf(-vals[0]));
        float sn  = g2 * vals[1] + (1.0f - g2) * vals[4];
        float sn2 = g2 * g2 * vals[2] + 2.0f * g2 * (1.0f - g2) * vals[3]
                  + (1.0f - g2) * (1.0f - g2) * vals[5];
        float m   = sn * (1.0f / 128.0f);
        float var = sn2 * (1.0f / 128.0f) - m * m;
        float n2 = y * g2 + n1 * (1.0f - g2);
        if (own) {
            nodes[bn * DIMM + d] = n2;
            s_xh[d] = __float2half((n2 - m) * rsqrtf(var + 1e-5f) * ln1_g[(l + 1) * DIMM + d]
                                   + ln1_b[(l + 1) * DIMM + d]);
        }
        __syncthreads();

        int col = w * 64 + ln;
        // ---------- Wq' / Wk' / Wv' back-to-back, zero barriers ----------
        wait_vm<0>();
        {
            float q = gemv512T<1>(s_xh, wbuf, WknL, (char*)wbuf, ln);
            qb[(size_t)bn * INNER + col] = q + bq[(l + 1) * INNER + col];
        }
        wait_vm<0>();
        {
            float kk = gemv512T<1>(s_xh, wbuf, WvnL, (char*)wbuf, ln);
            hkout[(size_t)bn * INNER + col] =
                __float2half(kk + bkv[(l + 1) * 2 * INNER + col]);
        }
        wait_vm<0>();
        {
            float vv = gemv512T<0>(s_xh, wbuf, nullptr, nullptr, ln);
            hvout[(size_t)bn * INNER + col] =
                __float2half(vv + bkv[(l + 1) * 2 * INNER + INNER + col]);
        }
    } else {
        // ---------- fused gate2 + final contribution ----------
        float wl = own ? Wlin[d] : 0.0f;
        float tex = own ? (y * Wg2_l[d] + n1 * Wg2_l[DIMM + d]
                           + (y - n1) * Wg2_l[2 * DIMM + d]) : 0.0f;
        float vals[3] = {tex, y * wl, n1 * wl};
        block_reduce_n<3>(vals, s_red);
        float g2 = 1.0f / (1.0f + __expf(-vals[0]));
        float tot = g2 * vals[1] + (1.0f - g2) * vals[2];
        if (t == 0) atomicAdd(out, tot);
    }
}

extern "C" void kernel_launch(void* const* d_in, const int* in_sizes, int n_in,
                              void* d_out, int out_size, void* d_ws, size_t ws_size,
                              hipStream_t stream) {
    const int*   indices = (const int*)d_in[0];
    const float* coords  = (const float*)d_in[1];
    const int*   bonds   = (const int*)d_in[2];
    const float* noise   = (const float*)d_in[3];
    const float* atom_emb= (const float*)d_in[4];
    const float* ln1_g   = (const float*)d_in[5];
    const float* ln1_b   = (const float*)d_in[6];
    const float* Wq      = (const float*)d_in[7];
    const float* bq      = (const float*)d_in[8];
    const float* Wkv     = (const float*)d_in[9];
    const float* bkv     = (const float*)d_in[10];
    const float* We      = (const float*)d_in[11];
    const float* be      = (const float*)d_in[12];
    const float* Wo      = (const float*)d_in[13];
    const float* bo      = (const float*)d_in[14];
    const float* Wg1     = (const float*)d_in[15];
    const float* ln2_g   = (const float*)d_in[16];
    const float* ln2_b   = (const float*)d_in[17];
    const float* W1      = (const float*)d_in[18];
    const float* b1      = (const float*)d_in[19];
    const float* W2      = (const float*)d_in[20];
    const float* b2      = (const float*)d_in[21];
    const float* Wg2     = (const float*)d_in[22];
    const float* Wlin    = (const float*)d_in[23];
    const float* blin    = (const float*)d_in[24];

    float*  ws    = (float*)d_ws;
    float*  nodes = ws;                         // 32768 f
    float*  qb    = nodes + NNODE * DIMM;       // 131072 f
    __half* hkb   = (__half*)(qb + NNODE * INNER);  // 2 slabs x 131072 halves
    __half* hvb   = hkb + 2 * NNODE * INNER;
    __half* hWq   = hvb + 2 * NNODE * INNER;
    __half* hWkv  = hWq + DEPTH * DIMM * INNER;
    __half* hWo   = hWkv + DEPTH * DIMM * 2 * INNER;
    __half* hW1   = hWo + DEPTH * INNER * DIMM;
    __half* hW2   = hW1 + DEPTH * DIMM * 4 * DIMM;

    k_cvt<<<288, 512, 0, stream>>>(Wq, Wkv, Wo, W1, W2, hWq, hWkv, hWo, hW1, hW2,
                                   blin, (float*)d_out);
    k_pre<<<NNODE, 512, 0, stream>>>(indices, noise, atom_emb, ln1_g, ln1_b,
                                     hWq, bq, hWkv, bkv, nodes, qb, hkb, hvb);
    for (int l = 0; l < DEPTH; l++) {
        const __half* hkin = hkb + (size_t)(l & 1) * NNODE * INNER;
        const __half* hvin = hvb + (size_t)(l & 1) * NNODE * INNER;
        __half* hkout = hkb + (size_t)((l + 1) & 1) * NNODE * INNER;
        __half* hvout = hvb + (size_t)((l + 1) & 1) * NNODE * INNER;
        k_layer<<<NNODE, 512, 0, stream>>>(l, coords, bonds, We, be,
                                           qb, hkin, hvin, hkout, hvout,
                                           hWo, bo, Wg1, ln2_g, ln2_b, hW1, b1, hW2, b2,
                                           Wg2, ln1_g, ln1_b, hWq, bq, hWkv, bkv,
                                           nodes, Wlin, (float*)d_out);
    }
}

// Round 5
// 244.535 us; speedup vs baseline: 1.1804x; 1.0032x over previous
//
#include <hip/hip_runtime.h>
#include <hip/hip_fp16.h>
#include <math.h>

#define DEPTH 6
#define NN    128
#define EE    160
#define NF    127
#define DIMM  128
#define INNER 512
#define NNODE 256

typedef _Float16 h2f16 __attribute__((ext_vector_type(2)));

#if defined(__has_builtin)
#if __has_builtin(__builtin_amdgcn_fdot2)
#define HAVE_FDOT2 1
#endif
#endif

__device__ __forceinline__ float fdot2f(h2f16 a, h2f16 b, float c) {
#ifdef HAVE_FDOT2
    return __builtin_amdgcn_fdot2(a, b, c, false);
#else
    return c + (float)a.x * (float)b.x + (float)a.y * (float)b.y;
#endif
}

__device__ __forceinline__ void gload16(const void* g, void* l) {
    __builtin_amdgcn_global_load_lds((const __attribute__((address_space(1))) void*)g,
                                     (__attribute__((address_space(3))) void*)l,
                                     16, 0, 0);
}

// s_waitcnt: vmcnt<=N, exp/lgkm unconstrained. gfx9 encoding:
// vmcnt[3:0]=bits3:0, exp=bits6:4, lgkm=bits11:8, vmcnt[5:4]=bits15:14.
template <int N>
__device__ __forceinline__ void wait_vm() {
    __builtin_amdgcn_s_waitcnt((0xF << 8) | (7 << 4) | (N & 0xF) | ((N >> 4) << 14));
}
__device__ __forceinline__ void wait_lgkm0() { __builtin_amdgcn_s_waitcnt(0xC07F); }
__device__ __forceinline__ void sbar0() { __builtin_amdgcn_sched_barrier(0); }

// 8 KB contiguous half-slice: 8 x (1 KB) DMA calls, linear LDS dest.
__device__ __forceinline__ void stage8c(const char* g, char* lds, int ln) {
#pragma unroll
    for (int i = 0; i < 8; i++)
        gload16(g + i * 1024 + ln * 16, lds + i * 1024);
}
// 8 rows of 1 KB, global row stride rs bytes (f32 staging in k_pre).
__device__ __forceinline__ void stage8f(const char* g, int rs, char* lds, int ln) {
#pragma unroll
    for (int i = 0; i < 8; i++)
        gload16(g + (size_t)i * rs + ln * 16, lds + i * 1024);
}

// ---- chunked transposed-f16 GEMV units (combine-free, A/B rolling window) ----
// Slab layout (written by the cvt prologue in k_pre):
//   slice w = 16 KB = 16 chunks x 1 KB; chunk i = K-rows [8i,8i+8) of all 64
//   lane-columns; lane ln's 16 B at chunk + ln*16 (contiguous wave read).
// Discipline at entry: this matrix's A (chunks 0-7) and B (8-15) in flight,
// A oldest. vm<=8 -> A landed. read A; drain lds; stage next.A; vm<=8 -> B
// landed; read B; drain; stage next.B; compute. In-order vmem retirement makes
// the counted waits exact (interleaved loads/stores only over-wait, never race).

// C=512, K=128. Lane output col = w*64+ln. x = 128 halves (16 B per chunk).
template <int NXT>
__device__ __forceinline__ float gemv512v2(const __half* s_xh, float* wbuf,
                                           const char* nextG, int ln) {
    const char* Wb = (const char*)wbuf;
    float4 wa[8], wb[8];
    wait_vm<8>();
#pragma unroll
    for (int i = 0; i < 8; i++) wa[i] = *(const float4*)(Wb + i * 1024 + ln * 16);
    sbar0(); wait_lgkm0(); sbar0();
    if (NXT) { stage8c(nextG, (char*)wbuf, ln); wait_vm<8>(); }
    else     wait_vm<0>();
#pragma unroll
    for (int i = 0; i < 8; i++) wb[i] = *(const float4*)(Wb + 8192 + i * 1024 + ln * 16);
    sbar0(); wait_lgkm0(); sbar0();
    if (NXT) stage8c(nextG + 8192, (char*)wbuf + 8192, ln);
    const float4* X = (const float4*)s_xh;
    float a0 = 0, a1 = 0, a2 = 0, a3 = 0;
#pragma unroll
    for (int i = 0; i < 8; i++) {
        float4 xv = X[i];
        const h2f16* wh = (const h2f16*)&wa[i];
        const h2f16* xh = (const h2f16*)&xv;
        a0 = fdot2f(xh[0], wh[0], a0); a1 = fdot2f(xh[1], wh[1], a1);
        a2 = fdot2f(xh[2], wh[2], a2); a3 = fdot2f(xh[3], wh[3], a3);
    }
#pragma unroll
    for (int i = 0; i < 8; i++) {
        float4 xv = X[8 + i];
        const h2f16* wh = (const h2f16*)&wb[i];
        const h2f16* xh = (const h2f16*)&xv;
        a0 = fdot2f(xh[0], wh[0], a0); a1 = fdot2f(xh[1], wh[1], a1);
        a2 = fdot2f(xh[2], wh[2], a2); a3 = fdot2f(xh[3], wh[3], a3);
    }
    return (a0 + a1) + (a2 + a3);
}

// C=128, K=512. Lane: col = w*16+(ln>>2), kq = ln&3 owns rows kq*128+[0,128).
// x kq-padded: half idx = (row>>7)*136 + (row&127). Caller combines 4 partials
// with shfl_xor(1)+shfl_xor(2).
template <int NXT>
__device__ __forceinline__ float gemv128v2(const __half* s_xp, float* wbuf,
                                           const char* nextG, int ln) {
    const char* Wb = (const char*)wbuf;
    const char* Xb = (const char*)s_xp + (ln & 3) * 272;
    float4 wa[8], wb[8];
    wait_vm<8>();
#pragma unroll
    for (int i = 0; i < 8; i++) wa[i] = *(const float4*)(Wb + i * 1024 + ln * 16);
    sbar0(); wait_lgkm0(); sbar0();
    if (NXT) { stage8c(nextG, (char*)wbuf, ln); wait_vm<8>(); }
    else     wait_vm<0>();
#pragma unroll
    for (int i = 0; i < 8; i++) wb[i] = *(const float4*)(Wb + 8192 + i * 1024 + ln * 16);
    sbar0(); wait_lgkm0(); sbar0();
    if (NXT) stage8c(nextG + 8192, (char*)wbuf + 8192, ln);
    float a0 = 0, a1 = 0, a2 = 0, a3 = 0;
#pragma unroll
    for (int i = 0; i < 8; i++) {
        float4 xv = *(const float4*)(Xb + i * 16);
        const h2f16* wh = (const h2f16*)&wa[i];
        const h2f16* xh = (const h2f16*)&xv;
        a0 = fdot2f(xh[0], wh[0], a0); a1 = fdot2f(xh[1], wh[1], a1);
        a2 = fdot2f(xh[2], wh[2], a2); a3 = fdot2f(xh[3], wh[3], a3);
    }
#pragma unroll
    for (int i = 0; i < 8; i++) {
        float4 xv = *(const float4*)(Xb + 128 + i * 16);
        const h2f16* wh = (const h2f16*)&wb[i];
        const h2f16* xh = (const h2f16*)&xv;
        a0 = fdot2f(xh[0], wh[0], a0); a1 = fdot2f(xh[1], wh[1], a1);
        a2 = fdot2f(xh[2], wh[2], a2); a3 = fdot2f(xh[3], wh[3], a3);
    }
    return (a0 + a1) + (a2 + a3);
}

// f32 K-split GEMV for k_pre (reads original row-major f32 weights).
// Wave w owns K-rows [w*16,+16) of a 256-col half; slice = 16 rows x 1 KB.
template <int NXT>
__device__ __forceinline__ float4 gemvf32(const float* s_xn, float* wbuf,
                                          const char* nextG, int nrs, int w, int ln) {
    const float4* w4 = (const float4*)wbuf;
    float4 wr[16];
    wait_vm<8>();
#pragma unroll
    for (int r = 0; r < 8; r++) wr[r] = w4[r * 64 + ln];
    sbar0(); wait_lgkm0(); sbar0();
    if (NXT) { stage8f(nextG, nrs, (char*)wbuf, ln); wait_vm<8>(); }
    else     wait_vm<0>();
#pragma unroll
    for (int r = 8; r < 16; r++) wr[r] = w4[r * 64 + ln];
    sbar0(); wait_lgkm0(); sbar0();
    if (NXT) stage8f(nextG + (size_t)8 * nrs, nrs, (char*)wbuf + 8192, ln);
    float4 acc = {0, 0, 0, 0};
#pragma unroll
    for (int r = 0; r < 16; r++) {
        float a = s_xn[w * 16 + r];
        acc.x += a * wr[r].x; acc.y += a * wr[r].y;
        acc.z += a * wr[r].z; acc.w += a * wr[r].w;
    }
    return acc;
}

// N-value block reduce (8 waves); results broadcast into vals[].
template <int N>
__device__ __forceinline__ void block_reduce_n(float* vals, float* sbuf) {
#pragma unroll
    for (int off = 32; off > 0; off >>= 1)
#pragma unroll
        for (int q = 0; q < N; q++) vals[q] += __shfl_xor(vals[q], off, 64);
    int wave = threadIdx.x >> 6;
    if ((threadIdx.x & 63) == 0)
#pragma unroll
        for (int q = 0; q < N; q++) sbuf[wave * N + q] = vals[q];
    __syncthreads();
#pragma unroll
    for (int q = 0; q < N; q++) {
        float r = 0.0f;
#pragma unroll
        for (int g = 0; g < 8; g++) r += sbuf[g * N + q];
        vals[q] = r;
    }
    __syncthreads();
}

__device__ __forceinline__ float gelu_exact(float a) {
    return 0.5f * a * (1.0f + erff(a * 0.70710678f));
}

// ---------- k_pre: weight cvt prologue + sedge precompute + node-0 QKV ----------
__global__ __launch_bounds__(512, 1) void k_pre(
        const int* indices, const float* coords, const int* bonds, const float* noise,
        const float* atom_emb, const float* ln1_g, const float* ln1_b,
        const float* Wq, const float* bq, const float* Wkv, const float* bkv,
        const float* Wo, const float* W1, const float* W2,
        __half* hWq, __half* hWkv, __half* hWo, __half* hW1, __half* hW2,
        float* nodes, float* qb, __half* hk, __half* hv, float* sedgews,
        const float* blin, float* out) {
    int bn = blockIdx.x;
    int b = bn >> 7, i = bn & 127;
    int t  = threadIdx.x;
    int d  = t & 127;
    bool own = (t < 128);
    int w = t >> 6, ln = t & 63;
    __shared__ float arena[32768];     // 8 waves x 16 KB f32 slices
    __shared__ float scoord[384];
    __shared__ int   sadj[128];
    __shared__ float s_xn[128];
    __shared__ float s_red[48];
    __shared__ float s_part[2048];
    float* wbuf = arena + w * 4096;
    char*  wbufc = (char*)wbuf;

    if (bn == 0 && t == 0) out[0] = 256.0f * blin[0];

    // f32 QKV phase table: {q lo, q hi, k lo, k hi, v lo, v hi}
    const char* phB[6] = {(const char*)Wq,            (const char*)Wq + 1024,
                          (const char*)Wkv,           (const char*)Wkv + 1024,
                          (const char*)Wkv + 2048,    (const char*)Wkv + 3072};
    const int phRS[6] = {2048, 2048, 4096, 4096, 4096, 4096};

    // stage phase 0 (A then B); lands during setup + cvt below
    stage8f(phB[0] + (size_t)(w * 16) * phRS[0], phRS[0], wbufc, ln);
    stage8f(phB[0] + (size_t)(w * 16 + 8) * phRS[0], phRS[0], wbufc + 8192, ln);

    // ---- one-time setup: coords, adjacency, masked edge row -> ws ----
    if (t < 3 * NN) scoord[t] = coords[b * 3 * NN + t];
    if (t < NN) sadj[t] = 0;
    __syncthreads();
    if (t < EE) {
        int e0 = bonds[2 * t], e1 = bonds[2 * t + 1];
        if (e0 == i) sadj[e1] = 1;
        if (e1 == i) sadj[e0] = 1;
    }
    __syncthreads();
    if (t < NN) {
        int j = t;
        float msk = sadj[j] ? 1.0f : 0.0f;
        sedgews[bn * 384 + 3 * j + 0] = msk * (scoord[3 * i + 0] - scoord[3 * j + 0]);
        sedgews[bn * 384 + 3 * j + 1] = msk * (scoord[3 * i + 1] - scoord[3 * j + 1]);
        sedgews[bn * 384 + 3 * j + 2] = msk * (scoord[3 * i + 2] - scoord[3 * j + 2]);
    }

    // ---- gather + LN1(0) ----
    float nd = 0.0f;
    if (own) {
        int idx = indices[bn];
        nd = (d < NF) ? atom_emb[idx * NF + d] : noise[0];
        nodes[bn * DIMM + d] = nd;
    }
    {
        float vals[2] = {own ? nd : 0.0f, own ? nd * nd : 0.0f};
        block_reduce_n<2>(vals, s_red);
        float m   = vals[0] * (1.0f / 128.0f);
        float var = vals[1] * (1.0f / 128.0f) - m * m;
        if (own) s_xn[d] = (nd - m) * rsqrtf(var + 1e-5f) * ln1_g[d] + ln1_b[d];
    }

    // ---- cvt prologue: f32 -> chunked transposed f16 slabs (all 6 layers) ----
    // unit = 8 rows x 1 col (one 16-B dst write); 294912 units grid-strided.
    for (int u = bn * 512 + t; u < 294912; u += NNODE * 512) {
        int s = u >> 13, within = u & 8191;
        int l = s / 6, m = s % 6;
        const float* src; __half* dst; int ncols, colofs, big;
        if (m == 0)      { src = Wq  + (size_t)l * 65536;  dst = hWq  + (size_t)l * 65536;         ncols = 512;  colofs = 0;   big = 0; }
        else if (m == 1) { src = Wkv + (size_t)l * 131072; dst = hWkv + (size_t)l * 131072;        ncols = 1024; colofs = 0;   big = 0; }
        else if (m == 2) { src = Wkv + (size_t)l * 131072; dst = hWkv + (size_t)l * 131072 + 65536;ncols = 1024; colofs = 512; big = 0; }
        else if (m == 3) { src = W1  + (size_t)l * 65536;  dst = hW1  + (size_t)l * 65536;         ncols = 512;  colofs = 0;   big = 0; }
        else if (m == 4) { src = Wo  + (size_t)l * 65536;  dst = hWo  + (size_t)l * 65536;         ncols = 128;  colofs = 0;   big = 1; }
        else             { src = W2  + (size_t)l * 65536;  dst = hW2  + (size_t)l * 65536;         ncols = 128;  colofs = 0;   big = 1; }
        int rb, col;
        if (!big) { rb = within >> 9; col = within & 511; }
        else      { rb = within >> 7; col = within & 127; }
        int row0 = rb * 8;
        __align__(16) __half tmp[8];
#pragma unroll
        for (int e = 0; e < 8; e++)
            tmp[e] = __float2half(src[(size_t)(row0 + e) * ncols + colofs + col]);
        int dh;
        if (!big) dh = (col >> 6) * 8192 + rb * 512 + (col & 63) * 8;
        else {
            int kq = row0 >> 7, ci = (row0 & 127) >> 3;
            dh = (col >> 4) * 8192 + ci * 512 + ((col & 15) * 4 + kq) * 8;
        }
        *(float4*)&dst[dh] = *(const float4*)tmp;
    }
    __syncthreads();

    // ---- QKV from f32 weights, 6 half-phases with rolling staging ----
#define PRE_COMBINE(P)                                                        \
    {                                                                         \
        ((float4*)(s_part + w * 256))[ln] = acc;                              \
        __syncthreads();                                                      \
        if (t < 256) {                                                        \
            float sS = 0.0f;                                                  \
            _Pragma("unroll")                                                 \
            for (int g = 0; g < 8; g++) sS += s_part[g * 256 + t];            \
            int col = ((P) & 1) * 256 + t;                                    \
            if ((P) < 2)      qb[(size_t)bn * INNER + col] = sS + bq[col];    \
            else if ((P) < 4) hk[(size_t)bn * INNER + col] =                  \
                                  __float2half(sS + bkv[col]);                \
            else              hv[(size_t)bn * INNER + col] =                  \
                                  __float2half(sS + bkv[INNER + col]);        \
        }                                                                     \
        __syncthreads();                                                      \
    }

    {
        float4 acc;
        acc = gemvf32<1>(s_xn, wbuf, phB[1] + (size_t)(w * 16) * phRS[1], phRS[1], w, ln);
        PRE_COMBINE(0);
        acc = gemvf32<1>(s_xn, wbuf, phB[2] + (size_t)(w * 16) * phRS[2], phRS[2], w, ln);
        PRE_COMBINE(1);
        acc = gemvf32<1>(s_xn, wbuf, phB[3] + (size_t)(w * 16) * phRS[3], phRS[3], w, ln);
        PRE_COMBINE(2);
        acc = gemvf32<1>(s_xn, wbuf, phB[4] + (size_t)(w * 16) * phRS[4], phRS[4], w, ln);
        PRE_COMBINE(3);
        acc = gemvf32<1>(s_xn, wbuf, phB[5] + (size_t)(w * 16) * phRS[5], phRS[5], w, ln);
        PRE_COMBINE(4);
        acc = gemvf32<0>(s_xn, wbuf, nullptr, 0, w, ln);
        PRE_COMBINE(5);
    }
#undef PRE_COMBINE
}

__global__ __launch_bounds__(512, 1) void k_layer(int l,
        const float* sedgews,
        const float* We, const float* be,
        float* qb, const __half* hkin, const __half* hvin,
        __half* hkout, __half* hvout,
        const __half* hWo, const float* bo, const float* Wg1,
        const float* ln2_g, const float* ln2_b,
        const __half* hW1, const float* b1,
        const __half* hW2, const float* b2,
        const float* Wg2,
        const float* ln1_g, const float* ln1_b,
        const __half* hWq, const float* bq,
        const __half* hWkv, const float* bkv,
        float* nodes, const float* Wlin, float* out) {
    int bn = blockIdx.x;
    int b = bn >> 7;
    int t = threadIdx.x;
    int d = t & 127;
    bool own = (t < 128);
    int w = t >> 6, ln = t & 63;

    __shared__ float arena[32768];     // 8 waves x 16 KB weight slices
    __shared__ float sedge[384];
    __shared__ float s_l[64];
    __shared__ __align__(16) __half s_aoh[544];   // kq-padded (4 x 136)
    __shared__ __align__(16) __half s_hh[544];    // kq-padded
    __shared__ __align__(16) __half s_xh[128];
    __shared__ float s_x[128];
    __shared__ float s_red[48];
    __shared__ float s_part[4096];     // attention o-combine only
    float* s_o = s_part;
    float* wbuf = arena + w * 4096;

    const char* WoL  = (const char*)hWo + (size_t)l * 131072 + w * 16384;
    const char* W1L  = (const char*)hW1 + (size_t)l * 131072 + w * 16384;
    const char* W2L  = (const char*)hW2 + (size_t)l * 131072 + w * 16384;
    const char* WqnL = (const char*)hWq + (size_t)(l + 1) * 131072 + w * 16384;
    const char* WknL = (const char*)hWkv + (size_t)(l + 1) * 262144 + w * 16384;
    const char* WvnL = (const char*)hWkv + (size_t)(l + 1) * 262144 + 131072 + w * 16384;

    // stage Wo (A then B); lands during the attention phase
    stage8c(WoL, (char*)wbuf, ln);
    stage8c(WoL + 8192, (char*)wbuf + 8192, ln);

    // ---------- attention: wave w owns j in [w*16, w*16+16); 64 lanes = 512 dims ----------
    const float4* qR4 = (const float4*)(qb + (size_t)bn * INNER);
    const float4* WeR = (const float4*)(We + (size_t)l * 3 * INNER);
    float4 qa  = qR4[ln * 2],        qz  = qR4[ln * 2 + 1];
    float4 w0a = WeR[ln * 2],        w0z = WeR[ln * 2 + 1];
    float4 w1a = WeR[128 + ln * 2],  w1z = WeR[129 + ln * 2];
    float4 w2a = WeR[256 + ln * 2],  w2z = WeR[257 + ln * 2];
    float4 bea = ((const float4*)(be + (size_t)l * INNER))[ln * 2];
    float4 bez = ((const float4*)(be + (size_t)l * INNER))[ln * 2 + 1];
    float res = own ? nodes[bn * DIMM + d] : 0.0f;
    h2f16 qh0 = {(_Float16)qa.x, (_Float16)qa.y};
    h2f16 qh1 = {(_Float16)qa.z, (_Float16)qa.w};
    h2f16 qh2 = {(_Float16)qz.x, (_Float16)qz.y};
    h2f16 qh3 = {(_Float16)qz.z, (_Float16)qz.w};
    // per-head q.be (non-bonded j have e == be exactly)
    float c = qa.x * bea.x + qa.y * bea.y + qa.z * bea.z + qa.w * bea.w
            + qz.x * bez.x + qz.y * bez.y + qz.z * bez.z + qz.w * bez.w;
    c += __shfl_xor(c, 1, 64); c += __shfl_xor(c, 2, 64); c += __shfl_xor(c, 4, 64);

    if (t < 384) sedge[t] = sedgews[bn * 384 + t];
    __syncthreads();

    const float4* kR = (const float4*)(hkin + (size_t)b * NN * INNER);   // 8 halves/elt
    const float4* vR = (const float4*)(hvin + (size_t)b * NN * INNER);
    float l_run = 0.0f, S_nb = 0.0f;
    float4 o0 = {0, 0, 0, 0}, o1 = {0, 0, 0, 0};
    int j0 = w * 16;
#pragma unroll
    for (int base = 0; base < 16; base += 4) {
        float4 kraw[4], vraw[4];
#pragma unroll
        for (int p = 0; p < 4; p++) {
            int j = j0 + base + p;
            kraw[p] = kR[j * 64 + ln];
            vraw[p] = vR[j * 64 + ln];
        }
#pragma unroll
        for (int p = 0; p < 4; p++) {
            int j = j0 + base + p;
            const h2f16* kh = (const h2f16*)&kraw[p];
            float s = fdot2f(qh0, kh[0],
                      fdot2f(qh1, kh[1],
                      fdot2f(qh2, kh[2],
                      fdot2f(qh3, kh[3], 0.0f))));
            float ex = sedge[3 * j], ey = sedge[3 * j + 1], ez = sedge[3 * j + 2];
            bool bonded = (ex != 0.0f) || (ey != 0.0f) || (ez != 0.0f);  // wave-uniform
            float4 e0, e1;
            if (bonded) {
                e0.x = bea.x + ex * w0a.x + ey * w1a.x + ez * w2a.x;
                e0.y = bea.y + ex * w0a.y + ey * w1a.y + ez * w2a.y;
                e0.z = bea.z + ex * w0a.z + ey * w1a.z + ez * w2a.z;
                e0.w = bea.w + ex * w0a.w + ey * w1a.w + ez * w2a.w;
                e1.x = bez.x + ex * w0z.x + ey * w1z.x + ez * w2z.x;
                e1.y = bez.y + ex * w0z.y + ey * w1z.y + ez * w2z.y;
                e1.z = bez.z + ex * w0z.z + ey * w1z.z + ez * w2z.z;
                e1.w = bez.w + ex * w0z.w + ey * w1z.w + ez * w2z.w;
                s += qa.x * e0.x + qa.y * e0.y + qa.z * e0.z + qa.w * e0.w
                   + qz.x * e1.x + qz.y * e1.y + qz.z * e1.z + qz.w * e1.w;
            }
            s += __shfl_xor(s, 1, 64);
            s += __shfl_xor(s, 2, 64);
            s += __shfl_xor(s, 4, 64);
            if (!bonded) s += c;
            float pp = __expf(s * 0.125f);
            l_run += pp;
            const __half2* vh = (const __half2*)&vraw[p];
            float2 v0 = __half22float2(vh[0]), v1 = __half22float2(vh[1]);
            float2 v2 = __half22float2(vh[2]), v3 = __half22float2(vh[3]);
            o0.x += pp * v0.x; o0.y += pp * v0.y; o0.z += pp * v1.x; o0.w += pp * v1.y;
            o1.x += pp * v2.x; o1.y += pp * v2.y; o1.z += pp * v3.x; o1.w += pp * v3.y;
            if (bonded) {
                o0.x += pp * e0.x; o0.y += pp * e0.y; o0.z += pp * e0.z; o0.w += pp * e0.w;
                o1.x += pp * e1.x; o1.y += pp * e1.y; o1.z += pp * e1.z; o1.w += pp * e1.w;
            } else S_nb += pp;
        }
    }
    // fold the shared be contribution of all non-bonded j
    o0.x += S_nb * bea.x; o0.y += S_nb * bea.y; o0.z += S_nb * bea.z; o0.w += S_nb * bea.w;
    o1.x += S_nb * bez.x; o1.y += S_nb * bez.y; o1.z += S_nb * bez.z; o1.w += S_nb * bez.w;
    ((float4*)(s_o + w * 512))[ln * 2]     = o0;
    ((float4*)(s_o + w * 512))[ln * 2 + 1] = o1;
    if ((ln & 7) == 0) s_l[w * 8 + (ln >> 3)] = l_run;
    __syncthreads();
    {
        float o = 0.0f;
#pragma unroll
        for (int g = 0; g < 8; g++) o += s_o[g * 512 + t];
        int h = t >> 6;
        float lsum = 0.0f;
#pragma unroll
        for (int g = 0; g < 8; g++) lsum += s_l[g * 8 + h];
        s_aoh[(t >> 7) * 136 + (t & 127)] = __float2half(o / lsum);
    }
    __syncthreads();

    // ---------- Wo [512 x 128] (stages W1 mid-phase) ----------
    {
        float xo = gemv128v2<1>(s_aoh, wbuf, W1L, ln);
        xo += __shfl_xor(xo, 1, 64);
        xo += __shfl_xor(xo, 2, 64);
        if ((ln & 3) == 0) s_x[w * 16 + (ln >> 2)] = xo;
    }
    __syncthreads();
    float x = own ? s_x[d] + bo[l * DIMM + d] : 0.0f;

    // ---------- fused gate1 + LN2 (single reduce pass) ----------
    const float* Wg1_l = Wg1 + l * 3 * DIMM;
    float n1;
    {
        float tex = own ? (x * Wg1_l[d] + res * Wg1_l[DIMM + d]
                           + (x - res) * Wg1_l[2 * DIMM + d]) : 0.0f;
        float vals[6] = {tex,
                         own ? x : 0.0f, own ? x * x : 0.0f,
                         own ? x * res : 0.0f,
                         own ? res : 0.0f, own ? res * res : 0.0f};
        block_reduce_n<6>(vals, s_red);
        float g1 = 1.0f / (1.0f + __expf(-vals[0]));
        float sn  = g1 * vals[1] + (1.0f - g1) * vals[4];
        float sn2 = g1 * g1 * vals[2] + 2.0f * g1 * (1.0f - g1) * vals[3]
                  + (1.0f - g1) * (1.0f - g1) * vals[5];
        float m   = sn * (1.0f / 128.0f);
        float var = sn2 * (1.0f / 128.0f) - m * m;
        n1 = x * g1 + res * (1.0f - g1);
        if (own) s_xh[d] = __float2half((n1 - m) * rsqrtf(var + 1e-5f) * ln2_g[l * DIMM + d]
                                        + ln2_b[l * DIMM + d]);
    }
    __syncthreads();

    // ---------- W1 [128 x 512] + gelu (stages W2 mid-phase) ----------
    {
        float a1 = gemv512v2<1>(s_xh, wbuf, W2L, ln);
        int col = w * 64 + ln;
        float ag = gelu_exact(a1 + b1[l * 4 * DIMM + col]);
        s_hh[(col >> 7) * 136 + (col & 127)] = __float2half(ag);
    }
    __syncthreads();

    // ---------- W2 [512 x 128] (stages next-layer Wq if needed) ----------
    {
        float yw;
        if (l < DEPTH - 1) yw = gemv128v2<1>(s_hh, wbuf, WqnL, ln);
        else               yw = gemv128v2<0>(s_hh, wbuf, nullptr, ln);
        yw += __shfl_xor(yw, 1, 64);
        yw += __shfl_xor(yw, 2, 64);
        if ((ln & 3) == 0) s_x[w * 16 + (ln >> 2)] = yw;
    }
    __syncthreads();
    float y = own ? s_x[d] + b2[l * DIMM + d] : 0.0f;

    const float* Wg2_l = Wg2 + l * 3 * DIMM;
    if (l < DEPTH - 1) {
        // ---------- fused gate2 + LN1' (single reduce pass) ----------
        float tex = own ? (y * Wg2_l[d] + n1 * Wg2_l[DIMM + d]
                           + (y - n1) * Wg2_l[2 * DIMM + d]) : 0.0f;
        float vals[6] = {tex,
                         own ? y : 0.0f, own ? y * y : 0.0f,
                         own ? y * n1 : 0.0f,
                         own ? n1 : 0.0f, own ? n1 * n1 : 0.0f};
        block_reduce_n<6>(vals, s_red);
        float g2 = 1.0f / (1.0f + __expf(-vals[0]));
        float sn  = g2 * vals[1] + (1.0f - g2) * vals[4];
        float sn2 = g2 * g2 * vals[2] + 2.0f * g2 * (1.0f - g2) * vals[3]
                  + (1.0f - g2) * (1.0f - g2) * vals[5];
        float m   = sn * (1.0f / 128.0f);
        float var = sn2 * (1.0f / 128.0f) - m * m;
        float n2 = y * g2 + n1 * (1.0f - g2);
        if (own) {
            nodes[bn * DIMM + d] = n2;
            s_xh[d] = __float2half((n2 - m) * rsqrtf(var + 1e-5f) * ln1_g[(l + 1) * DIMM + d]
                                   + ln1_b[(l + 1) * DIMM + d]);
        }
        __syncthreads();

        int col = w * 64 + ln;
        // ---------- Wq' / Wk' / Wv' back-to-back, zero barriers ----------
        {
            float q = gemv512v2<1>(s_xh, wbuf, WknL, ln);
            qb[(size_t)bn * INNER + col] = q + bq[(l + 1) * INNER + col];
        }
        {
            float kk = gemv512v2<1>(s_xh, wbuf, WvnL, ln);
            hkout[(size_t)bn * INNER + col] =
                __float2half(kk + bkv[(l + 1) * 2 * INNER + col]);
        }
        {
            float vv = gemv512v2<0>(s_xh, wbuf, nullptr, ln);
            hvout[(size_t)bn * INNER + col] =
                __float2half(vv + bkv[(l + 1) * 2 * INNER + INNER + col]);
        }
    } else {
        // ---------- fused gate2 + final contribution ----------
        float wl = own ? Wlin[d] : 0.0f;
        float tex = own ? (y * Wg2_l[d] + n1 * Wg2_l[DIMM + d]
                           + (y - n1) * Wg2_l[2 * DIMM + d]) : 0.0f;
        float vals[3] = {tex, y * wl, n1 * wl};
        block_reduce_n<3>(vals, s_red);
        float g2 = 1.0f / (1.0f + __expf(-vals[0]));
        float tot = g2 * vals[1] + (1.0f - g2) * vals[2];
        if (t == 0) atomicAdd(out, tot);
    }
}

extern "C" void kernel_launch(void* const* d_in, const int* in_sizes, int n_in,
                              void* d_out, int out_size, void* d_ws, size_t ws_size,
                              hipStream_t stream) {
    const int*   indices = (const int*)d_in[0];
    const float* coords  = (const float*)d_in[1];
    const int*   bonds   = (const int*)d_in[2];
    const float* noise   = (const float*)d_in[3];
    const float* atom_emb= (const float*)d_in[4];
    const float* ln1_g   = (const float*)d_in[5];
    const float* ln1_b   = (const float*)d_in[6];
    const float* Wq      = (const float*)d_in[7];
    const float* bq      = (const float*)d_in[8];
    const float* Wkv     = (const float*)d_in[9];
    const float* bkv     = (const float*)d_in[10];
    const float* We      = (const float*)d_in[11];
    const float* be      = (const float*)d_in[12];
    const float* Wo      = (const float*)d_in[13];
    const float* bo      = (const float*)d_in[14];
    const float* Wg1     = (const float*)d_in[15];
    const float* ln2_g   = (const float*)d_in[16];
    const float* ln2_b   = (const float*)d_in[17];
    const float* W1      = (const float*)d_in[18];
    const float* b1      = (const float*)d_in[19];
    const float* W2      = (const float*)d_in[20];
    const float* b2      = (const float*)d_in[21];
    const float* Wg2     = (const float*)d_in[22];
    const float* Wlin    = (const float*)d_in[23];
    const float* blin    = (const float*)d_in[24];

    float*  ws    = (float*)d_ws;
    float*  nodes = ws;                         // 32768 f
    float*  qb    = nodes + NNODE * DIMM;       // 131072 f
    __half* hkb   = (__half*)(qb + NNODE * INNER);  // 2 slabs x 131072 halves
    __half* hvb   = hkb + 2 * NNODE * INNER;
    __half* hWq   = hvb + 2 * NNODE * INNER;
    __half* hWkv  = hWq + DEPTH * DIMM * INNER;
    __half* hWo   = hWkv + DEPTH * DIMM * 2 * INNER;
    __half* hW1   = hWo + DEPTH * INNER * DIMM;
    __half* hW2   = hW1 + DEPTH * DIMM * 4 * DIMM;
    float*  sedgews = (float*)(hW2 + DEPTH * 4 * DIMM * DIMM);   // 256*384 f

    k_pre<<<NNODE, 512, 0, stream>>>(indices, coords, bonds, noise, atom_emb,
                                     ln1_g, ln1_b, Wq, bq, Wkv, bkv, Wo, W1, W2,
                                     hWq, hWkv, hWo, hW1, hW2,
                                     nodes, qb, hkb, hvb, sedgews, blin, (float*)d_out);
    for (int l = 0; l < DEPTH; l++) {
        const __half* hkin = hkb + (size_t)(l & 1) * NNODE * INNER;
        const __half* hvin = hvb + (size_t)(l & 1) * NNODE * INNER;
        __half* hkout = hkb + (size_t)((l + 1) & 1) * NNODE * INNER;
        __half* hvout = hvb + (size_t)((l + 1) & 1) * NNODE * INNER;
        k_layer<<<NNODE, 512, 0, stream>>>(l, sedgews, We, be,
                                           qb, hkin, hvin, hkout, hvout,
                                           hWo, bo, Wg1, ln2_g, ln2_b, hW1, b1, hW2, b2,
                                           Wg2, ln1_g, ln1_b, hWq, bq, hWkv, bkv,
                                           nodes, Wlin, (float*)d_out);
    }
}